// Round 1
// baseline (692.592 us; speedup 1.0000x reference)
//
#include <hip/hip_runtime.h>
#include <stdint.h>
#include <math.h>

typedef uint32_t u32;
typedef uint64_t u64;

#define BB 8
#define CAT 10
#define HH 512
#define WW 512
#define HW (HH * WW)          // 262144
#define KSEL 500
#define NB 8192               // histogram buckets (value-linear over [0,1))
#define PF_BUCKET 8110        // static prefilter threshold bucket (~v >= 0.98999)
#define PRECAP 4096           // per-(b,c) prefilter buffer capacity
#define CANDCAP 2048          // candidate sort capacity (power of 2)

// order-preserving float->u32 (ascending)
__device__ __forceinline__ u32 f2u(float f) {
    u32 b = __float_as_uint(f);
    return (b & 0x80000000u) ? ~b : (b | 0x80000000u);
}
__device__ __forceinline__ float u2f(u32 u) {
    u32 b = (u & 0x80000000u) ? (u ^ 0x80000000u) : ~u;
    return __uint_as_float(b);
}
// exactly monotone bucket map (mul by 8192 is exact: power-of-two scale)
__device__ __forceinline__ int bucketOf(float v) {
    int b = (int)floorf(v * (float)NB);
    return min(max(b, 0), NB - 1);
}

// ---------------- Kernel A: histogram + static prefilter (single heat read) --------
__global__ __launch_bounds__(512) void k_hist(const float* __restrict__ heat,
                                              u32* __restrict__ hist,
                                              u32* __restrict__ precnt,
                                              u64* __restrict__ prebuf) {
    const int bc = blockIdx.y;       // 0..79
    const int chunk = blockIdx.x;    // 0..3
    const int tid = threadIdx.x;
    __shared__ u32 lh[NB];
    for (int i = tid; i < NB; i += 512) lh[i] = 0;
    __syncthreads();

    const float4* hp = (const float4*)(heat + (size_t)bc * HW + (size_t)chunk * (HW / 4));
    const int base_idx = chunk * (HW / 4);
    u32* pc = precnt + bc;
    u64* pb = prebuf + (size_t)bc * PRECAP;

    // 65536 elems per chunk = 16384 float4 = 32 iters of 512 threads
    for (int it = 0; it < 32; ++it) {
        int i4 = it * 512 + tid;
        float4 v = hp[i4];
        int e0 = base_idx + i4 * 4;
        float vv[4] = {v.x, v.y, v.z, v.w};
#pragma unroll
        for (int j = 0; j < 4; ++j) {
            int bk = bucketOf(vv[j]);
            atomicAdd(&lh[bk], 1u);
            if (bk >= PF_BUCKET) {
                u32 pos = atomicAdd(pc, 1u);
                if (pos < PRECAP)
                    pb[pos] = ((u64)f2u(vv[j]) << 32) | (u32)(~(u32)(e0 + j));
            }
        }
    }
    __syncthreads();
    u32* gh = hist + (size_t)bc * NB;
    for (int i = tid; i < NB; i += 512) {
        u32 c = lh[i];
        if (c) atomicAdd(&gh[i], c);
    }
}

// shared helper: given LDS histogram h[NB], find boundary bucket b1 = max q with
// (count of elements in buckets >= q) >= KSEL.  Uses ps0/ps1 scratch. 1024 threads.
__device__ __forceinline__ int find_b1(u32* h, u32* ps0, u32* ps1, int* b1_s) {
    const int tid = threadIdx.x;
    u32 p = 0;
#pragma unroll
    for (int q = 0; q < 8; ++q) p += h[tid * 8 + q];
    ps0[tid] = p;
    __syncthreads();
    u32* src = ps0;
    u32* dst = ps1;
    for (int off = 1; off < 1024; off <<= 1) {
        u32 v = src[tid] + ((tid + off < 1024) ? src[tid + off] : 0);
        dst[tid] = v;
        __syncthreads();
        u32* t = src; src = dst; dst = t;
    }
    u32 S_t = src[tid];
    u32 S_next = (tid < 1023) ? src[tid + 1] : 0;
    if (S_t >= KSEL && (tid == 1023 || S_next < KSEL)) {
        u32 run = (tid == 1023) ? 0u : S_next;
        int b1 = tid * 8;
        for (int q = 7; q >= 0; --q) {
            run += h[tid * 8 + q];
            if (run >= KSEL) { b1 = tid * 8 + q; break; }
        }
        *b1_s = b1;
    }
    __syncthreads();
    return *b1_s;
}

// bitonic sort descending of cand[CANDCAP] (u64 keys), 1024 threads
__device__ __forceinline__ void bitonic_sort_desc(u64* cand) {
    const int tid = threadIdx.x;
    for (int k2 = 2; k2 <= CANDCAP; k2 <<= 1) {
        for (int j = k2 >> 1; j > 0; j >>= 1) {
            for (int i = tid; i < CANDCAP; i += 1024) {
                int ixj = i ^ j;
                if (ixj > i) {
                    u64 a = cand[i], b = cand[ixj];
                    bool up = ((i & k2) == 0);
                    if ((a < b) == up) { cand[i] = b; cand[ixj] = a; }
                }
            }
            __syncthreads();
        }
    }
}

// ---------------- Kernel B: stage-1 select + sort per (b,c) --------
__global__ __launch_bounds__(1024) void k_select1(const float* __restrict__ heat,
                                                  const u32* __restrict__ hist,
                                                  const u32* __restrict__ precnt,
                                                  const u64* __restrict__ prebuf,
                                                  u64* __restrict__ s1keys) {
    const int bc = blockIdx.x;
    const int tid = threadIdx.x;
    __shared__ u32 h[NB];
    __shared__ u32 ps0[1024], ps1[1024];
    __shared__ u64 cand[CANDCAP];
    __shared__ int b1_s;
    __shared__ int cnt_s;

    const u32* gh = hist + (size_t)bc * NB;
    for (int i = tid; i < NB; i += 1024) h[i] = gh[i];
    if (tid == 0) cnt_s = 0;
    __syncthreads();

    int b1 = find_b1(h, ps0, ps1, &b1_s);

    u32 pcnt = precnt[bc];
    bool fast = (b1 >= PF_BUCKET) && (pcnt <= PRECAP);
    if (fast) {
        const u64* pb = prebuf + (size_t)bc * PRECAP;
        for (int i = tid; i < (int)pcnt; i += 1024) {
            u64 kk = pb[i];
            float v = u2f((u32)(kk >> 32));
            if (bucketOf(v) >= b1) {
                int pos = atomicAdd(&cnt_s, 1);
                if (pos < CANDCAP) cand[pos] = kk;
            }
        }
    } else {
        const float* hp = heat + (size_t)bc * HW;
        for (int i = tid; i < HW; i += 1024) {
            float v = hp[i];
            if (bucketOf(v) >= b1) {
                int pos = atomicAdd(&cnt_s, 1);
                if (pos < CANDCAP)
                    cand[pos] = ((u64)f2u(v) << 32) | (u32)(~(u32)i);
            }
        }
    }
    __syncthreads();
    int cnt = min(cnt_s, CANDCAP);
    for (int i = cnt + tid; i < CANDCAP; i += 1024) cand[i] = 0;
    __syncthreads();

    bitonic_sort_desc(cand);

    if (tid < KSEL) s1keys[(size_t)bc * KSEL + tid] = cand[tid];
}

// ---------------- Kernel C: stage-2 select + decode + write outputs --------
__global__ __launch_bounds__(1024) void k_stage2(const u64* __restrict__ s1keys,
                                                 const float* __restrict__ rot_sine,
                                                 const float* __restrict__ rot_cosine,
                                                 const float* __restrict__ hei,
                                                 const float* __restrict__ dim,
                                                 const float* __restrict__ vel,
                                                 const float* __restrict__ reg,
                                                 float* __restrict__ out) {
    const int b = blockIdx.x;
    const int tid = threadIdx.x;
    const int NCAND = CAT * KSEL;   // 5000
    __shared__ u32 h[NB];
    __shared__ u32 ps0[1024], ps1[1024];
    __shared__ u64 cand[CANDCAP];
    __shared__ int b1_s;
    __shared__ int cnt_s;

    for (int i = tid; i < NB; i += 1024) h[i] = 0;
    if (tid == 0) cnt_s = 0;
    __syncthreads();

    const u64* sk = s1keys + (size_t)b * NCAND;
    for (int i = tid; i < NCAND; i += 1024) {
        float v = u2f((u32)(sk[i] >> 32));
        atomicAdd(&h[bucketOf(v)], 1u);
    }
    __syncthreads();

    int b1 = find_b1(h, ps0, ps1, &b1_s);

    for (int i = tid; i < NCAND; i += 1024) {
        u64 k1 = sk[i];
        float v = u2f((u32)(k1 >> 32));
        if (bucketOf(v) >= b1) {
            int pos = atomicAdd(&cnt_s, 1);
            if (pos < CANDCAP)
                cand[pos] = (k1 & 0xFFFFFFFF00000000ull) | (u32)(~(u32)i);
        }
    }
    __syncthreads();
    int cnt = min(cnt_s, CANDCAP);
    for (int i = cnt + tid; i < CANDCAP; i += 1024) cand[i] = 0;
    __syncthreads();

    bitonic_sort_desc(cand);
    __syncthreads();

    if (tid < KSEL) {
        u64 kk = cand[tid];
        u32 u = (u32)(kk >> 32);
        float score = u2f(u);
        int flat = (int)(~(u32)kk);              // 0..4999
        int cls = flat / KSEL;
        int ridx = (int)(~(u32)sk[flat]);        // spatial index 0..262143
        float xs = (float)(ridx % WW);
        float ys = (float)(ridx / WW);
        size_t base = (size_t)b * HW;
        float r0 = reg[((size_t)(b * 2 + 0)) * HW + ridx];
        float r1 = reg[((size_t)(b * 2 + 1)) * HW + ridx];
        float rs = rot_sine[base + ridx];
        float rc = rot_cosine[base + ridx];
        float hg = hei[base + ridx];
        float d0 = dim[((size_t)(b * 3 + 0)) * HW + ridx];
        float d1 = dim[((size_t)(b * 3 + 1)) * HW + ridx];
        float d2 = dim[((size_t)(b * 3 + 2)) * HW + ridx];
        float v0 = vel[((size_t)(b * 2 + 0)) * HW + ridx];
        float v1 = vel[((size_t)(b * 2 + 1)) * HW + ridx];

        float x = (xs + r0) * 0.8f + (-51.2f);
        float y = (ys + r1) * 0.8f + (-51.2f);
        float rot = atan2f(rs, rc);

        size_t obase = ((size_t)b * KSEL + tid) * 9;
        out[obase + 0] = x;
        out[obase + 1] = y;
        out[obase + 2] = hg;
        out[obase + 3] = d0;
        out[obase + 4] = d1;
        out[obase + 5] = d2;
        out[obase + 6] = rot;
        out[obase + 7] = v0;
        out[obase + 8] = v1;

        const int NOUT = BB * KSEL;              // 4000
        out[9 * NOUT + b * KSEL + tid] = score;
        out[10 * NOUT + b * KSEL + tid] = (float)cls;
        bool keep = (x >= -61.2f) && (y >= -61.2f) && (hg >= -10.0f) &&
                    (x <= 61.2f) && (y <= 61.2f) && (hg <= 10.0f) &&
                    (score > 0.1f);
        out[11 * NOUT + b * KSEL + tid] = keep ? 1.0f : 0.0f;
    }
}

extern "C" void kernel_launch(void* const* d_in, const int* in_sizes, int n_in,
                              void* d_out, int out_size, void* d_ws, size_t ws_size,
                              hipStream_t stream) {
    const float* heat       = (const float*)d_in[0];
    const float* rot_sine   = (const float*)d_in[1];
    const float* rot_cosine = (const float*)d_in[2];
    const float* hei        = (const float*)d_in[3];
    const float* dim        = (const float*)d_in[4];
    const float* vel        = (const float*)d_in[5];
    const float* reg        = (const float*)d_in[6];

    char* ws = (char*)d_ws;
    // layout: hist 80*8192*4 = 2621440 | precnt 80*4 = 320 | prebuf 80*4096*8 = 2621440 | s1keys 80*500*8
    u32* hist   = (u32*)ws;
    u32* precnt = (u32*)(ws + 2621440);
    u64* prebuf = (u64*)(ws + 2621760);
    u64* s1keys = (u64*)(ws + 5243200);

    hipMemsetAsync(ws, 0, 2621760, stream);   // zero hist + precnt each call (no cross-call state)

    k_hist<<<dim3(4, BB * CAT), 512, 0, stream>>>(heat, hist, precnt, prebuf);
    k_select1<<<dim3(BB * CAT), 1024, 0, stream>>>(heat, hist, precnt, prebuf, s1keys);
    k_stage2<<<dim3(BB), 1024, 0, stream>>>(s1keys, rot_sine, rot_cosine, hei, dim, vel, reg,
                                            (float*)d_out);
}

// Round 2
// 104.449 us; speedup vs baseline: 6.6309x; 6.6309x over previous
//
#include <hip/hip_runtime.h>
#include <stdint.h>
#include <math.h>

typedef uint32_t u32;
typedef uint64_t u64;

#define BB 8
#define CAT 10
#define HH 512
#define WW 512
#define HW (HH * WW)          // 262144
#define KSEL 500
#define NB 8192               // histogram buckets (slow path only)
#define PRECAP 2048           // per-(b,c) candidate buffer capacity
#define CANDCAP 2048          // sort capacity (power of 2)
#define LCAP 256              // per-WG LDS candidate capacity
#define WGCH 32               // chunks per plane (kernel A)
#define THRV 0.9954f          // static prefilter: expect ~1206/plane, in [500,2048] at >20 sigma

// order-preserving float->u32 (ascending)
__device__ __forceinline__ u32 f2u(float f) {
    u32 b = __float_as_uint(f);
    return (b & 0x80000000u) ? ~b : (b | 0x80000000u);
}
__device__ __forceinline__ float u2f(u32 u) {
    u32 b = (u & 0x80000000u) ? (u ^ 0x80000000u) : ~u;
    return __uint_as_float(b);
}
// exactly monotone bucket map (mul by 8192 is exact: power-of-two scale)
__device__ __forceinline__ int bucketOf(float v) {
    int b = (int)floorf(v * (float)NB);
    return min(max(b, 0), NB - 1);
}

// ---------------- Kernel A: streaming prefilter (single heat read, no histogram) ----
__global__ __launch_bounds__(256) void k_prefilter(const float* __restrict__ heat,
                                                   u32* __restrict__ gcnt,
                                                   u32* __restrict__ oflow,
                                                   u64* __restrict__ prebuf) {
    const int bc = blockIdx.y;       // 0..79
    const int chunk = blockIdx.x;    // 0..WGCH-1
    const int tid = threadIdx.x;
    __shared__ u64 lbuf[LCAP];
    __shared__ u32 lcnt;
    __shared__ u32 gbase;
    if (tid == 0) lcnt = 0;
    __syncthreads();

    const int CH = HW / WGCH;        // 8192 elems per chunk
    const float4* hp = (const float4*)(heat + (size_t)bc * HW + (size_t)chunk * CH);
    const int base_idx = chunk * CH;

#pragma unroll
    for (int it = 0; it < CH / (256 * 4); ++it) {   // 8 fully-unrolled float4 loads in flight
        int i4 = it * 256 + tid;
        float4 v = hp[i4];
        int e0 = base_idx + i4 * 4;
        float vv[4] = {v.x, v.y, v.z, v.w};
#pragma unroll
        for (int j = 0; j < 4; ++j) {
            if (vv[j] > THRV) {
                u32 pos = atomicAdd(&lcnt, 1u);
                if (pos < LCAP)
                    lbuf[pos] = ((u64)f2u(vv[j]) << 32) | (u32)(~(u32)(e0 + j));
            }
        }
    }
    __syncthreads();
    u32 n = lcnt > LCAP ? LCAP : lcnt;
    if (tid == 0) {
        if (lcnt > LCAP) oflow[bc] = 1;            // dropped candidates -> exact fallback
        gbase = atomicAdd(&gcnt[bc], n);           // ONE global atomic per WG
    }
    __syncthreads();
    u64* pb = prebuf + (size_t)bc * PRECAP;
    for (u32 i = tid; i < n; i += 256) {
        u32 pos = gbase + i;
        if (pos < PRECAP) pb[pos] = lbuf[i];
        else oflow[bc] = 1;
    }
}

// find boundary bucket b1 = max q with suffix-count(q) >= KSEL. 1024 threads.
__device__ __forceinline__ int find_b1(u32* h, u32* ps0, u32* ps1, int* b1_s) {
    const int tid = threadIdx.x;
    u32 p = 0;
#pragma unroll
    for (int q = 0; q < 8; ++q) p += h[tid * 8 + q];
    ps0[tid] = p;
    __syncthreads();
    u32* src = ps0;
    u32* dst = ps1;
    for (int off = 1; off < 1024; off <<= 1) {
        u32 v = src[tid] + ((tid + off < 1024) ? src[tid + off] : 0);
        dst[tid] = v;
        __syncthreads();
        u32* t = src; src = dst; dst = t;
    }
    u32 S_t = src[tid];
    u32 S_next = (tid < 1023) ? src[tid + 1] : 0;
    if (S_t >= KSEL && (tid == 1023 || S_next < KSEL)) {
        u32 run = (tid == 1023) ? 0u : S_next;
        int b1 = tid * 8;
        for (int q = 7; q >= 0; --q) {
            run += h[tid * 8 + q];
            if (run >= KSEL) { b1 = tid * 8 + q; break; }
        }
        *b1_s = b1;
    }
    __syncthreads();
    return *b1_s;
}

// bitonic sort descending of cand[CANDCAP] (u64 keys), 1024 threads
__device__ __forceinline__ void bitonic_sort_desc(u64* cand) {
    const int tid = threadIdx.x;
    for (int k2 = 2; k2 <= CANDCAP; k2 <<= 1) {
        for (int j = k2 >> 1; j > 0; j >>= 1) {
            for (int i = tid; i < CANDCAP; i += 1024) {
                int ixj = i ^ j;
                if (ixj > i) {
                    u64 a = cand[i], b = cand[ixj];
                    bool up = ((i & k2) == 0);
                    if ((a < b) == up) { cand[i] = b; cand[ixj] = a; }
                }
            }
            __syncthreads();
        }
    }
}

// ---------------- Kernel B: per-(b,c) sort of prefiltered candidates ----
__global__ __launch_bounds__(1024) void k_select1(const float* __restrict__ heat,
                                                  const u32* __restrict__ gcnt,
                                                  const u32* __restrict__ oflow,
                                                  const u64* __restrict__ prebuf,
                                                  u64* __restrict__ s1keys) {
    const int bc = blockIdx.x;
    const int tid = threadIdx.x;
    __shared__ u64 cand[CANDCAP];
    __shared__ u32 h[NB];
    __shared__ u32 ps0[1024], ps1[1024];
    __shared__ int b1_s;
    __shared__ int cnt_s;

    u32 cnt = gcnt[bc];
    u32 of = oflow[bc];
    bool fast = (of == 0) && (cnt >= KSEL) && (cnt <= CANDCAP);   // uniform across WG

    if (fast) {
        const u64* pb = prebuf + (size_t)bc * PRECAP;
        for (int i = tid; i < CANDCAP; i += 1024)
            cand[i] = (i < (int)cnt) ? pb[i] : 0;
        __syncthreads();
        bitonic_sort_desc(cand);
        if (tid < KSEL) s1keys[(size_t)bc * KSEL + tid] = cand[tid];
        return;
    }

    // exact fallback: per-plane histogram (never taken for this data, kept for correctness)
    for (int i = tid; i < NB; i += 1024) h[i] = 0;
    if (tid == 0) cnt_s = 0;
    __syncthreads();
    const float* hp = heat + (size_t)bc * HW;
    for (int i = tid; i < HW; i += 1024) atomicAdd(&h[bucketOf(hp[i])], 1u);
    __syncthreads();
    int b1 = find_b1(h, ps0, ps1, &b1_s);
    for (int i = tid; i < HW; i += 1024) {
        float v = hp[i];
        if (bucketOf(v) >= b1) {
            int pos = atomicAdd(&cnt_s, 1);
            if (pos < CANDCAP)
                cand[pos] = ((u64)f2u(v) << 32) | (u32)(~(u32)i);
        }
    }
    __syncthreads();
    int c2 = min(cnt_s, CANDCAP);
    for (int i = c2 + tid; i < CANDCAP; i += 1024) cand[i] = 0;
    __syncthreads();
    bitonic_sort_desc(cand);
    if (tid < KSEL) s1keys[(size_t)bc * KSEL + tid] = cand[tid];
}

// ---------------- Kernel C: stage-2 select + decode + write outputs --------
__global__ __launch_bounds__(1024) void k_stage2(const u64* __restrict__ s1keys,
                                                 const float* __restrict__ rot_sine,
                                                 const float* __restrict__ rot_cosine,
                                                 const float* __restrict__ hei,
                                                 const float* __restrict__ dim,
                                                 const float* __restrict__ vel,
                                                 const float* __restrict__ reg,
                                                 float* __restrict__ out) {
    const int b = blockIdx.x;
    const int tid = threadIdx.x;
    const int NCAND = CAT * KSEL;   // 5000
    __shared__ u32 h[NB];
    __shared__ u32 ps0[1024], ps1[1024];
    __shared__ u64 cand[CANDCAP];
    __shared__ int b1_s;
    __shared__ int cnt_s;

    for (int i = tid; i < NB; i += 1024) h[i] = 0;
    if (tid == 0) cnt_s = 0;
    __syncthreads();

    const u64* sk = s1keys + (size_t)b * NCAND;
    for (int i = tid; i < NCAND; i += 1024) {
        float v = u2f((u32)(sk[i] >> 32));
        atomicAdd(&h[bucketOf(v)], 1u);
    }
    __syncthreads();

    int b1 = find_b1(h, ps0, ps1, &b1_s);

    for (int i = tid; i < NCAND; i += 1024) {
        u64 k1 = sk[i];
        float v = u2f((u32)(k1 >> 32));
        if (bucketOf(v) >= b1) {
            int pos = atomicAdd(&cnt_s, 1);
            if (pos < CANDCAP)
                cand[pos] = (k1 & 0xFFFFFFFF00000000ull) | (u32)(~(u32)i);
        }
    }
    __syncthreads();
    int cnt = min(cnt_s, CANDCAP);
    for (int i = cnt + tid; i < CANDCAP; i += 1024) cand[i] = 0;
    __syncthreads();

    bitonic_sort_desc(cand);
    __syncthreads();

    if (tid < KSEL) {
        u64 kk = cand[tid];
        u32 u = (u32)(kk >> 32);
        float score = u2f(u);
        int flat = (int)(~(u32)kk);              // 0..4999
        int cls = flat / KSEL;
        int ridx = (int)(~(u32)sk[flat]);        // spatial index 0..262143
        float xs = (float)(ridx % WW);
        float ys = (float)(ridx / WW);
        size_t base = (size_t)b * HW;
        float r0 = reg[((size_t)(b * 2 + 0)) * HW + ridx];
        float r1 = reg[((size_t)(b * 2 + 1)) * HW + ridx];
        float rs = rot_sine[base + ridx];
        float rc = rot_cosine[base + ridx];
        float hg = hei[base + ridx];
        float d0 = dim[((size_t)(b * 3 + 0)) * HW + ridx];
        float d1 = dim[((size_t)(b * 3 + 1)) * HW + ridx];
        float d2 = dim[((size_t)(b * 3 + 2)) * HW + ridx];
        float v0 = vel[((size_t)(b * 2 + 0)) * HW + ridx];
        float v1 = vel[((size_t)(b * 2 + 1)) * HW + ridx];

        float x = (xs + r0) * 0.8f + (-51.2f);
        float y = (ys + r1) * 0.8f + (-51.2f);
        float rot = atan2f(rs, rc);

        size_t obase = ((size_t)b * KSEL + tid) * 9;
        out[obase + 0] = x;
        out[obase + 1] = y;
        out[obase + 2] = hg;
        out[obase + 3] = d0;
        out[obase + 4] = d1;
        out[obase + 5] = d2;
        out[obase + 6] = rot;
        out[obase + 7] = v0;
        out[obase + 8] = v1;

        const int NOUT = BB * KSEL;              // 4000
        out[9 * NOUT + b * KSEL + tid] = score;
        out[10 * NOUT + b * KSEL + tid] = (float)cls;
        bool keep = (x >= -61.2f) && (y >= -61.2f) && (hg >= -10.0f) &&
                    (x <= 61.2f) && (y <= 61.2f) && (hg <= 10.0f) &&
                    (score > 0.1f);
        out[11 * NOUT + b * KSEL + tid] = keep ? 1.0f : 0.0f;
    }
}

extern "C" void kernel_launch(void* const* d_in, const int* in_sizes, int n_in,
                              void* d_out, int out_size, void* d_ws, size_t ws_size,
                              hipStream_t stream) {
    const float* heat       = (const float*)d_in[0];
    const float* rot_sine   = (const float*)d_in[1];
    const float* rot_cosine = (const float*)d_in[2];
    const float* hei        = (const float*)d_in[3];
    const float* dim        = (const float*)d_in[4];
    const float* vel        = (const float*)d_in[5];
    const float* reg        = (const float*)d_in[6];

    char* ws = (char*)d_ws;
    // layout: gcnt 80*4 | oflow 80*4 | prebuf 80*2048*8 | s1keys 80*500*8
    u32* gcnt   = (u32*)ws;
    u32* oflow  = (u32*)(ws + 320);
    u64* prebuf = (u64*)(ws + 640);
    u64* s1keys = (u64*)(ws + 640 + 80 * PRECAP * 8);

    hipMemsetAsync(ws, 0, 640, stream);   // zero counters + overflow flags each call

    k_prefilter<<<dim3(WGCH, BB * CAT), 256, 0, stream>>>(heat, gcnt, oflow, prebuf);
    k_select1<<<dim3(BB * CAT), 1024, 0, stream>>>(heat, gcnt, oflow, prebuf, s1keys);
    k_stage2<<<dim3(BB), 1024, 0, stream>>>(s1keys, rot_sine, rot_cosine, hei, dim, vel, reg,
                                            (float*)d_out);
}

// Round 3
// 73.263 us; speedup vs baseline: 9.4535x; 1.4257x over previous
//
#include <hip/hip_runtime.h>
#include <stdint.h>
#include <math.h>

typedef uint32_t u32;
typedef uint64_t u64;

#define BB 8
#define CAT 10
#define HW 262144             // 512*512
#define WW 512
#define KSEL 500
#define NB 4096               // fallback histogram buckets
#define NBQ (NB / 1024)
#define CANDCAP 2048          // per-batch sort capacity (power of 2)
#define REGCAP 512            // per-plane region capacity in prebuf
#define LCAP 128              // per-WG LDS candidate capacity
#define WGCH 32               // WGs per plane in prefilter
#define THRV 0.9996f          // per-batch candidates ~1049 (sigma 32); per-plane ~105

// order-preserving float->u32 (ascending)
__device__ __forceinline__ u32 f2u(float f) {
    u32 b = __float_as_uint(f);
    return (b & 0x80000000u) ? ~b : (b | 0x80000000u);
}
__device__ __forceinline__ float u2f(u32 u) {
    u32 b = (u & 0x80000000u) ? (u ^ 0x80000000u) : ~u;
    return __uint_as_float(b);
}
__device__ __forceinline__ int bucketOf(float v) {   // exact monotone (pow2 scale)
    int b = (int)floorf(v * (float)NB);
    return min(max(b, 0), NB - 1);
}

// combined key: score desc, then (class asc, idx asc). combo = c*2^18+idx < 0x280000 <= 0x3FFFFF
__device__ __forceinline__ u64 make_key(float v, int c, int idx) {
    u32 combo = ((u32)c << 18) | (u32)idx;
    return ((u64)f2u(v) << 32) | (u32)(0x3FFFFFu - combo);
}

// ---------------- Kernel A: streaming prefilter (single 84MB heat read) ----
__global__ __launch_bounds__(256) void k_prefilter(const float* __restrict__ heat,
                                                   u32* __restrict__ plane_cnt,
                                                   u32* __restrict__ oflow,
                                                   u64* __restrict__ prebuf) {
    const int bc = blockIdx.y;       // 0..79
    const int chunk = blockIdx.x;    // 0..WGCH-1
    const int tid = threadIdx.x;
    const int b = bc / CAT, c = bc % CAT;
    __shared__ u64 lbuf[LCAP];
    __shared__ u32 lcnt;
    __shared__ u32 gbase;
    if (tid == 0) lcnt = 0;
    __syncthreads();

    const int CH = HW / WGCH;        // 8192 elems per chunk
    const float4* hp = (const float4*)(heat + (size_t)bc * HW + (size_t)chunk * CH);
    const int base_idx = chunk * CH;

#pragma unroll
    for (int it = 0; it < CH / (256 * 4); ++it) {   // 8 float4 loads, fully unrolled
        int i4 = it * 256 + tid;
        float4 v = hp[i4];
        int e0 = base_idx + i4 * 4;
        float vv[4] = {v.x, v.y, v.z, v.w};
#pragma unroll
        for (int j = 0; j < 4; ++j) {
            if (vv[j] > THRV) {
                u32 pos = atomicAdd(&lcnt, 1u);
                if (pos < LCAP) lbuf[pos] = make_key(vv[j], c, e0 + j);
            }
        }
    }
    __syncthreads();
    u32 n = lcnt > LCAP ? LCAP : lcnt;
    if (tid == 0) {
        if (lcnt > LCAP) oflow[b] = 1;             // dropped candidates -> exact fallback
        gbase = atomicAdd(&plane_cnt[bc], n);      // one global atomic per WG, 32-way/address
    }
    __syncthreads();
    u64* pb = prebuf + (size_t)bc * REGCAP;
    for (u32 i = tid; i < n; i += 256) {
        u32 pos = gbase + i;
        if (pos < REGCAP) pb[pos] = lbuf[i];
        else oflow[b] = 1;
    }
}

// find boundary bucket b1 = max q with suffix-count(q) >= KSEL. 1024 threads. (fallback only)
__device__ __forceinline__ int find_b1(u32* h, u32* ps0, u32* ps1, int* b1_s) {
    const int tid = threadIdx.x;
    u32 p = 0;
#pragma unroll
    for (int q = 0; q < NBQ; ++q) p += h[tid * NBQ + q];
    ps0[tid] = p;
    __syncthreads();
    u32* src = ps0;
    u32* dst = ps1;
    for (int off = 1; off < 1024; off <<= 1) {
        u32 v = src[tid] + ((tid + off < 1024) ? src[tid + off] : 0);
        dst[tid] = v;
        __syncthreads();
        u32* t = src; src = dst; dst = t;
    }
    u32 S_t = src[tid];
    u32 S_next = (tid < 1023) ? src[tid + 1] : 0;
    if (S_t >= KSEL && (tid == 1023 || S_next < KSEL)) {
        u32 run = (tid == 1023) ? 0u : S_next;
        int b1 = tid * NBQ;
        for (int q = NBQ - 1; q >= 0; --q) {
            run += h[tid * NBQ + q];
            if (run >= KSEL) { b1 = tid * NBQ + q; break; }
        }
        *b1_s = b1;
    }
    __syncthreads();
    return *b1_s;
}

// bitonic sort descending of cand[CANDCAP] (u64 keys), 1024 threads
__device__ __forceinline__ void bitonic_sort_desc(u64* cand) {
    const int tid = threadIdx.x;
    for (int k2 = 2; k2 <= CANDCAP; k2 <<= 1) {
        for (int j = k2 >> 1; j > 0; j >>= 1) {
            for (int i = tid; i < CANDCAP; i += 1024) {
                int ixj = i ^ j;
                if (ixj > i) {
                    u64 a = cand[i], b = cand[ixj];
                    bool up = ((i & k2) == 0);
                    if ((a < b) == up) { cand[i] = b; cand[ixj] = a; }
                }
            }
            __syncthreads();
        }
    }
}

// decode + write outputs for one winner (score, cls, ridx) at rank `rank` of batch b
__device__ __forceinline__ void decode_write(int b, int rank, float score, int cls, int ridx,
                                             const float* __restrict__ rot_sine,
                                             const float* __restrict__ rot_cosine,
                                             const float* __restrict__ hei,
                                             const float* __restrict__ dim,
                                             const float* __restrict__ vel,
                                             const float* __restrict__ reg,
                                             float* __restrict__ out) {
    float xs = (float)(ridx % WW);
    float ys = (float)(ridx / WW);
    size_t base = (size_t)b * HW;
    float r0 = reg[((size_t)(b * 2 + 0)) * HW + ridx];
    float r1 = reg[((size_t)(b * 2 + 1)) * HW + ridx];
    float rs = rot_sine[base + ridx];
    float rc = rot_cosine[base + ridx];
    float hg = hei[base + ridx];
    float d0 = dim[((size_t)(b * 3 + 0)) * HW + ridx];
    float d1 = dim[((size_t)(b * 3 + 1)) * HW + ridx];
    float d2 = dim[((size_t)(b * 3 + 2)) * HW + ridx];
    float v0 = vel[((size_t)(b * 2 + 0)) * HW + ridx];
    float v1 = vel[((size_t)(b * 2 + 1)) * HW + ridx];

    float x = (xs + r0) * 0.8f + (-51.2f);
    float y = (ys + r1) * 0.8f + (-51.2f);
    float rot = atan2f(rs, rc);

    size_t obase = ((size_t)b * KSEL + rank) * 9;
    out[obase + 0] = x;
    out[obase + 1] = y;
    out[obase + 2] = hg;
    out[obase + 3] = d0;
    out[obase + 4] = d1;
    out[obase + 5] = d2;
    out[obase + 6] = rot;
    out[obase + 7] = v0;
    out[obase + 8] = v1;

    const int NOUT = BB * KSEL;              // 4000
    out[9 * NOUT + b * KSEL + rank] = score;
    out[10 * NOUT + b * KSEL + rank] = (float)cls;
    bool keep = (x >= -61.2f) && (y >= -61.2f) && (hg >= -10.0f) &&
                (x <= 61.2f) && (y <= 61.2f) && (hg <= 10.0f) &&
                (score > 0.1f);
    out[11 * NOUT + b * KSEL + rank] = keep ? 1.0f : 0.0f;
}

// ---------------- Kernel B: per-batch single sort + decode (exact fallback inside) ----
__global__ __launch_bounds__(1024) void k_batch(const float* __restrict__ heat,
                                                const u32* __restrict__ plane_cnt,
                                                const u32* __restrict__ oflow,
                                                const u64* __restrict__ prebuf,
                                                const float* __restrict__ rot_sine,
                                                const float* __restrict__ rot_cosine,
                                                const float* __restrict__ hei,
                                                const float* __restrict__ dim,
                                                const float* __restrict__ vel,
                                                const float* __restrict__ reg,
                                                float* __restrict__ out) {
    const int b = blockIdx.x;
    const int tid = threadIdx.x;
    __shared__ u64 cand[CANDCAP];          // 16 KB
    __shared__ u32 pc[CAT], off[CAT];
    __shared__ u32 tot_s;
    __shared__ int fb;
    // fallback-only scratch (never touched on fast path)
    __shared__ u32 h[NB];                  // 16 KB
    __shared__ u32 ps0[1024], ps1[1024];   // 8 KB
    __shared__ u64 s1[CAT * KSEL];         // 40 KB
    __shared__ int b1_s;
    __shared__ int cnt_s;

    if (tid < CAT) pc[tid] = plane_cnt[b * CAT + tid];
    if (tid == 0) fb = (int)oflow[b];
    __syncthreads();
    if (tid == 0) {
        u32 tot = 0;
        for (int c = 0; c < CAT; ++c) {
            off[c] = tot;
            if (pc[c] > KSEL) fb = 1;      // class-rank constraint could bind
            tot += (pc[c] < REGCAP ? pc[c] : REGCAP);
        }
        if (tot < KSEL || tot > CANDCAP) fb = 1;
        tot_s = tot;
    }
    __syncthreads();

    if (!fb) {
        // ---- fast path: dense-load candidates, one sort, decode ----
        for (int c = 0; c < CAT; ++c) {
            const u64* pb = prebuf + (size_t)(b * CAT + c) * REGCAP;
            u32 n = pc[c];
            for (u32 i = tid; i < n; i += 1024) cand[off[c] + i] = pb[i];
        }
        for (u32 i = tot_s + tid; i < CANDCAP; i += 1024) cand[i] = 0;
        __syncthreads();
        bitonic_sort_desc(cand);
        if (tid < KSEL) {
            u64 kk = cand[tid];
            float score = u2f((u32)(kk >> 32));
            u32 combo = 0x3FFFFFu - (u32)(kk & 0xFFFFFFFFull);
            int cls = (int)(combo >> 18);
            int ridx = (int)(combo & 0x3FFFFu);
            decode_write(b, tid, score, cls, ridx,
                         rot_sine, rot_cosine, hei, dim, vel, reg, out);
        }
        return;
    }

    // ---- exact fallback (not taken for this data; correctness safety net) ----
    for (int c = 0; c < CAT; ++c) {
        const float* hp = heat + (size_t)(b * CAT + c) * HW;
        for (int i = tid; i < NB; i += 1024) h[i] = 0;
        if (tid == 0) cnt_s = 0;
        __syncthreads();
        for (int i = tid; i < HW; i += 1024) atomicAdd(&h[bucketOf(hp[i])], 1u);
        __syncthreads();
        int b1 = find_b1(h, ps0, ps1, &b1_s);
        for (int i = tid; i < HW; i += 1024) {
            float v = hp[i];
            if (bucketOf(v) >= b1) {
                int pos = atomicAdd(&cnt_s, 1);
                if (pos < CANDCAP)
                    cand[pos] = ((u64)f2u(v) << 32) | (u32)(~(u32)i);
            }
        }
        __syncthreads();
        int c2 = min(cnt_s, CANDCAP);
        for (int i = c2 + tid; i < CANDCAP; i += 1024) cand[i] = 0;
        __syncthreads();
        bitonic_sort_desc(cand);
        if (tid < KSEL) s1[c * KSEL + tid] = cand[tid];
        __syncthreads();
    }
    // stage 2 over s1[5000], tie-break by flat position
    const int NCAND = CAT * KSEL;
    for (int i = tid; i < NB; i += 1024) h[i] = 0;
    if (tid == 0) cnt_s = 0;
    __syncthreads();
    for (int i = tid; i < NCAND; i += 1024)
        atomicAdd(&h[bucketOf(u2f((u32)(s1[i] >> 32)))], 1u);
    __syncthreads();
    int b1 = find_b1(h, ps0, ps1, &b1_s);
    for (int i = tid; i < NCAND; i += 1024) {
        u64 k1 = s1[i];
        float v = u2f((u32)(k1 >> 32));
        if (bucketOf(v) >= b1) {
            int pos = atomicAdd(&cnt_s, 1);
            if (pos < CANDCAP)
                cand[pos] = (k1 & 0xFFFFFFFF00000000ull) | (u32)(~(u32)i);
        }
    }
    __syncthreads();
    int c2 = min(cnt_s, CANDCAP);
    for (int i = c2 + tid; i < CANDCAP; i += 1024) cand[i] = 0;
    __syncthreads();
    bitonic_sort_desc(cand);
    if (tid < KSEL) {
        u64 kk = cand[tid];
        float score = u2f((u32)(kk >> 32));
        int flat = (int)(~(u32)kk);
        int cls = flat / KSEL;
        int ridx = (int)(~(u32)s1[flat]);
        decode_write(b, tid, score, cls, ridx,
                     rot_sine, rot_cosine, hei, dim, vel, reg, out);
    }
}

extern "C" void kernel_launch(void* const* d_in, const int* in_sizes, int n_in,
                              void* d_out, int out_size, void* d_ws, size_t ws_size,
                              hipStream_t stream) {
    const float* heat       = (const float*)d_in[0];
    const float* rot_sine   = (const float*)d_in[1];
    const float* rot_cosine = (const float*)d_in[2];
    const float* hei        = (const float*)d_in[3];
    const float* dim        = (const float*)d_in[4];
    const float* vel        = (const float*)d_in[5];
    const float* reg        = (const float*)d_in[6];

    char* ws = (char*)d_ws;
    // layout: plane_cnt 80*4=320 | oflow 8*4=32 | pad to 512 | prebuf 80*512*8 = 320KB
    u32* plane_cnt = (u32*)ws;
    u32* oflow     = (u32*)(ws + 320);
    u64* prebuf    = (u64*)(ws + 512);

    hipMemsetAsync(ws, 0, 512, stream);   // zero counters + overflow flags each call

    k_prefilter<<<dim3(WGCH, BB * CAT), 256, 0, stream>>>(heat, plane_cnt, oflow, prebuf);
    k_batch<<<dim3(BB), 1024, 0, stream>>>(heat, plane_cnt, oflow, prebuf,
                                           rot_sine, rot_cosine, hei, dim, vel, reg,
                                           (float*)d_out);
}

// Round 4
// 37.532 us; speedup vs baseline: 18.4535x; 1.9520x over previous
//
#include <hip/hip_runtime.h>
#include <stdint.h>
#include <math.h>

typedef uint32_t u32;
typedef uint64_t u64;

#define BB 8
#define CAT 10
#define HW 262144             // 512*512
#define WW 512
#define KSEL 500
#define CHUNKS 32             // prefilter WGs per plane
#define NCH (CAT * CHUNKS)    // 320 chunk-regions per batch
#define LCAP 64               // per-chunk candidate capacity (mean 3.3, >20 sigma)
#define CANDCAP 2048          // per-batch candidate capacity (mean 1049, sigma 32)
#define SLICES 16             // k_rank WGs per batch; SLICES*128 == CANDCAP
#define THRV 0.9996f
#define NB 4096               // fallback histogram buckets
#define NBQ 16                // NB / 256

// order-preserving float->u32 (ascending)
__device__ __forceinline__ u32 f2u(float f) {
    u32 b = __float_as_uint(f);
    return (b & 0x80000000u) ? ~b : (b | 0x80000000u);
}
__device__ __forceinline__ float u2f(u32 u) {
    u32 b = (u & 0x80000000u) ? (u ^ 0x80000000u) : ~u;
    return __uint_as_float(b);
}
__device__ __forceinline__ int bucketOf(float v) {   // exact monotone (pow2 scale)
    int b = (int)floorf(v * (float)NB);
    return min(max(b, 0), NB - 1);
}
// combined key: score desc, then (class asc, idx asc); combo < 10*2^18 <= 0x3FFFFF
__device__ __forceinline__ u64 make_key(float v, int c, int idx) {
    u32 combo = ((u32)c << 18) | (u32)idx;
    return ((u64)f2u(v) << 32) | (u32)(0x3FFFFFu - combo);
}

// ---------------- Kernel A: streaming prefilter, private per-chunk regions ----
__global__ __launch_bounds__(256) void k_prefilter(const float* __restrict__ heat,
                                                   u32* __restrict__ cnts,
                                                   u64* __restrict__ prebuf) {
    const int bc = blockIdx.y;       // 0..79
    const int chunk = blockIdx.x;    // 0..CHUNKS-1
    const int tid = threadIdx.x;
    const int c = bc % CAT;
    __shared__ u32 lcnt;
    if (tid == 0) lcnt = 0;
    __syncthreads();

    const int CH = HW / CHUNKS;      // 8192
    const float4* hp = (const float4*)(heat + (size_t)bc * HW + (size_t)chunk * CH);
    const int base_idx = chunk * CH;
    u64* pb = prebuf + ((size_t)bc * CHUNKS + chunk) * LCAP;

#pragma unroll
    for (int it = 0; it < CH / (256 * 4); ++it) {   // 8 float4 loads, fully unrolled
        int i4 = it * 256 + tid;
        float4 v = hp[i4];
        int e0 = base_idx + i4 * 4;
        float vv[4] = {v.x, v.y, v.z, v.w};
#pragma unroll
        for (int j = 0; j < 4; ++j) {
            if (vv[j] > THRV) {
                u32 pos = atomicAdd(&lcnt, 1u);
                if (pos < LCAP) pb[pos] = make_key(vv[j], c, e0 + j);
            }
        }
    }
    __syncthreads();
    if (tid == 0) cnts[bc * CHUNKS + chunk] = lcnt;   // plain store; no memset needed
}

// ---- fallback helpers (256 threads) ----
__device__ __forceinline__ int find_b1_256(u32* h, u32* ps0, u32* ps1, int* b1_s) {
    const int tid = threadIdx.x;
    u32 p = 0;
#pragma unroll
    for (int q = 0; q < NBQ; ++q) p += h[tid * NBQ + q];
    ps0[tid] = p;
    __syncthreads();
    u32* src = ps0;
    u32* dst = ps1;
    for (int off = 1; off < 256; off <<= 1) {        // suffix scan
        u32 v = src[tid] + ((tid + off < 256) ? src[tid + off] : 0);
        dst[tid] = v;
        __syncthreads();
        u32* t = src; src = dst; dst = t;
    }
    u32 S_t = src[tid];
    u32 S_next = (tid < 255) ? src[tid + 1] : 0;
    if (S_t >= KSEL && (tid == 255 || S_next < KSEL)) {
        u32 run = (tid == 255) ? 0u : S_next;
        int b1 = tid * NBQ;
        for (int q = NBQ - 1; q >= 0; --q) {
            run += h[tid * NBQ + q];
            if (run >= KSEL) { b1 = tid * NBQ + q; break; }
        }
        *b1_s = b1;
    }
    __syncthreads();
    return *b1_s;
}

__device__ __forceinline__ void bitonic_sort_desc_256(u64* cand) {
    const int tid = threadIdx.x;
    for (int k2 = 2; k2 <= CANDCAP; k2 <<= 1) {
        for (int j = k2 >> 1; j > 0; j >>= 1) {
            for (int i = tid; i < CANDCAP; i += 256) {
                int ixj = i ^ j;
                if (ixj > i) {
                    u64 a = cand[i], b = cand[ixj];
                    bool up = ((i & k2) == 0);
                    if ((a < b) == up) { cand[i] = b; cand[ixj] = a; }
                }
            }
            __syncthreads();
        }
    }
}

// decode + write one winner at output slot `rank` of batch b
__device__ __forceinline__ void decode_write(int b, int rank, float score, int cls, int ridx,
                                             const float* __restrict__ rot_sine,
                                             const float* __restrict__ rot_cosine,
                                             const float* __restrict__ hei,
                                             const float* __restrict__ dim,
                                             const float* __restrict__ vel,
                                             const float* __restrict__ reg,
                                             float* __restrict__ out) {
    float xs = (float)(ridx % WW);
    float ys = (float)(ridx / WW);
    size_t base = (size_t)b * HW;
    float r0 = reg[((size_t)(b * 2 + 0)) * HW + ridx];
    float r1 = reg[((size_t)(b * 2 + 1)) * HW + ridx];
    float rs = rot_sine[base + ridx];
    float rc = rot_cosine[base + ridx];
    float hg = hei[base + ridx];
    float d0 = dim[((size_t)(b * 3 + 0)) * HW + ridx];
    float d1 = dim[((size_t)(b * 3 + 1)) * HW + ridx];
    float d2 = dim[((size_t)(b * 3 + 2)) * HW + ridx];
    float v0 = vel[((size_t)(b * 2 + 0)) * HW + ridx];
    float v1 = vel[((size_t)(b * 2 + 1)) * HW + ridx];

    float x = (xs + r0) * 0.8f + (-51.2f);
    float y = (ys + r1) * 0.8f + (-51.2f);
    float rot = atan2f(rs, rc);

    size_t obase = ((size_t)b * KSEL + rank) * 9;
    out[obase + 0] = x;
    out[obase + 1] = y;
    out[obase + 2] = hg;
    out[obase + 3] = d0;
    out[obase + 4] = d1;
    out[obase + 5] = d2;
    out[obase + 6] = rot;
    out[obase + 7] = v0;
    out[obase + 8] = v1;

    const int NOUT = BB * KSEL;              // 4000
    out[9 * NOUT + b * KSEL + rank] = score;
    out[10 * NOUT + b * KSEL + rank] = (float)cls;
    bool keep = (x >= -61.2f) && (y >= -61.2f) && (hg >= -10.0f) &&
                (x <= 61.2f) && (y <= 61.2f) && (hg <= 10.0f) &&
                (score > 0.1f);
    out[11 * NOUT + b * KSEL + rank] = keep ? 1.0f : 0.0f;
}

// ---------------- Kernel B: rank-count top-k + decode; exact fallback inside ----
__global__ __launch_bounds__(256) void k_rank(const float* __restrict__ heat,
                                              const u32* __restrict__ cnts,
                                              const u64* __restrict__ prebuf,
                                              const float* __restrict__ rot_sine,
                                              const float* __restrict__ rot_cosine,
                                              const float* __restrict__ hei,
                                              const float* __restrict__ dim,
                                              const float* __restrict__ vel,
                                              const float* __restrict__ reg,
                                              float* __restrict__ out) {
    const int b = blockIdx.y;
    const int slice = blockIdx.x;
    const int tid = threadIdx.x;

    __shared__ __align__(16) char smem[77824];          // 76 KB, manually overlaid
    // fast path layout
    u64* keys    = (u64*)smem;                          // [2048] 16 KB
    u32* cc      = (u32*)(smem + 16384);                // [320]
    u32* sc0     = (u32*)(smem + 17920);                // [512]
    u32* sc1     = (u32*)(smem + 19968);                // [512]
    u32* partial = (u32*)(smem + 22016);                // [256]
    // fallback overlay (cc/sc/partial dead once fallback starts)
    u32* h    = (u32*)smem;                             // [4096] 16 KB
    u64* cand = (u64*)(smem + 16384);                   // [2048] 16 KB
    u32* ps0  = (u32*)(smem + 32768);                   // [256]
    u32* ps1  = (u32*)(smem + 33792);                   // [256]
    u64* s1k  = (u64*)(smem + 34816);                   // [5000] 40 KB -> ends 74816
    __shared__ int fb_s;
    __shared__ int b1_s;
    __shared__ int cnt_s;

    if (tid == 0) fb_s = 0;
    __syncthreads();
    const u32* cb = cnts + b * NCH;
    for (int i = tid; i < NCH; i += 256) {
        u32 v = cb[i];
        cc[i] = v;
        if (v > LCAP) fb_s = 1;                         // same-value race OK
    }
    __syncthreads();
    // exclusive prefix over cc via Hillis-Steele inclusive scan of shifted array (512 wide)
    sc0[tid]       = (tid >= 1) ? cc[tid - 1] : 0;
    sc0[tid + 256] = (tid + 255 < NCH) ? cc[tid + 255] : 0;
    __syncthreads();
    u32* src = sc0; u32* dst = sc1;
    for (int off = 1; off < 512; off <<= 1) {
        for (int i = tid; i < 512; i += 256)
            dst[i] = src[i] + ((i >= off) ? src[i - off] : 0);
        __syncthreads();
        u32* t = src; src = dst; dst = t;
    }
    u32 tot = src[NCH];
    if (tot < KSEL || tot > CANDCAP) { if (tid == 0) fb_s = 1; }
    __syncthreads();
    int fb = fb_s;

    if (!fb) {
        // ---- fast path: compact keys into LDS, rank-count, scatter by rank ----
        for (int k = tid; k < NCH; k += 256) {
            u32 n = cc[k], off = src[k];
            const u64* pb = prebuf + ((size_t)b * NCH + k) * LCAP;
            for (u32 t = 0; t < n; ++t) keys[off + t] = pb[t];
        }
        for (int i = tid; i < CANDCAP; i += 256)
            if ((u32)i >= tot) keys[i] = 0;             // pad: never outranks real keys
        __syncthreads();

        const int ci  = slice * 128 + (tid & 127);
        const int sub = tid >> 7;                       // wave-uniform
        u64 mk = keys[ci];
        u32 mid = (tot + 1) >> 1;
        u32 j0 = sub ? mid : 0, j1 = sub ? tot : mid;
        u32 r = 0;
#pragma unroll 4
        for (u32 j = j0; j < j1; ++j) r += (keys[j] > mk);   // LDS broadcast reads
        partial[tid] = r;
        __syncthreads();
        if (tid < 128) {
            int rank = (int)(partial[tid] + partial[tid + 128]);
            int cix = slice * 128 + tid;
            if (cix < (int)tot && rank < KSEL) {
                u64 kk = keys[cix];
                float score = u2f((u32)(kk >> 32));
                u32 combo = 0x3FFFFFu - (u32)(kk & 0xFFFFFFFFull);
                int cls = (int)(combo >> 18);
                int ridx = (int)(combo & 0x3FFFFu);
                decode_write(b, rank, score, cls, ridx,
                             rot_sine, rot_cosine, hei, dim, vel, reg, out);
            }
        }
        return;
    }

    // ---- exact fallback (not taken for this data; correctness safety net) ----
    if (slice != 0) return;
    for (int c = 0; c < CAT; ++c) {
        const float* hp = heat + (size_t)(b * CAT + c) * HW;
        for (int i = tid; i < NB; i += 256) h[i] = 0;
        if (tid == 0) cnt_s = 0;
        __syncthreads();
        for (int i = tid; i < HW; i += 256) atomicAdd(&h[bucketOf(hp[i])], 1u);
        __syncthreads();
        int b1 = find_b1_256(h, ps0, ps1, &b1_s);
        for (int i = tid; i < HW; i += 256) {
            float v = hp[i];
            if (bucketOf(v) >= b1) {
                int pos = atomicAdd(&cnt_s, 1);
                if (pos < CANDCAP)
                    cand[pos] = ((u64)f2u(v) << 32) | (u32)(~(u32)i);
            }
        }
        __syncthreads();
        int c2 = min(cnt_s, CANDCAP);
        for (int i = c2 + tid; i < CANDCAP; i += 256) cand[i] = 0;
        __syncthreads();
        bitonic_sort_desc_256(cand);
        for (int r2 = tid; r2 < KSEL; r2 += 256) s1k[c * KSEL + r2] = cand[r2];
        __syncthreads();
    }
    // stage 2 over s1k[5000], tie-break by flat position
    const int NCAND = CAT * KSEL;
    for (int i = tid; i < NB; i += 256) h[i] = 0;
    if (tid == 0) cnt_s = 0;
    __syncthreads();
    for (int i = tid; i < NCAND; i += 256)
        atomicAdd(&h[bucketOf(u2f((u32)(s1k[i] >> 32)))], 1u);
    __syncthreads();
    int b1 = find_b1_256(h, ps0, ps1, &b1_s);
    for (int i = tid; i < NCAND; i += 256) {
        u64 k1 = s1k[i];
        float v = u2f((u32)(k1 >> 32));
        if (bucketOf(v) >= b1) {
            int pos = atomicAdd(&cnt_s, 1);
            if (pos < CANDCAP)
                cand[pos] = (k1 & 0xFFFFFFFF00000000ull) | (u32)(~(u32)i);
        }
    }
    __syncthreads();
    int c2 = min(cnt_s, CANDCAP);
    for (int i = c2 + tid; i < CANDCAP; i += 256) cand[i] = 0;
    __syncthreads();
    bitonic_sort_desc_256(cand);
    for (int r2 = tid; r2 < KSEL; r2 += 256) {
        u64 kk = cand[r2];
        float score = u2f((u32)(kk >> 32));
        int flat = (int)(~(u32)kk);
        int cls = flat / KSEL;
        int ridx = (int)(~(u32)s1k[flat]);
        decode_write(b, r2, score, cls, ridx,
                     rot_sine, rot_cosine, hei, dim, vel, reg, out);
    }
}

extern "C" void kernel_launch(void* const* d_in, const int* in_sizes, int n_in,
                              void* d_out, int out_size, void* d_ws, size_t ws_size,
                              hipStream_t stream) {
    const float* heat       = (const float*)d_in[0];
    const float* rot_sine   = (const float*)d_in[1];
    const float* rot_cosine = (const float*)d_in[2];
    const float* hei        = (const float*)d_in[3];
    const float* dim        = (const float*)d_in[4];
    const float* vel        = (const float*)d_in[5];
    const float* reg        = (const float*)d_in[6];

    char* ws = (char*)d_ws;
    // layout: cnts 80*32*4 = 10240 B | pad to 16384 | prebuf 80*32*64*8 = 1310720 B
    u32* cnts   = (u32*)ws;
    u64* prebuf = (u64*)(ws + 16384);
    // no memset needed: every cnt slot is written unconditionally by k_prefilter

    k_prefilter<<<dim3(CHUNKS, BB * CAT), 256, 0, stream>>>(heat, cnts, prebuf);
    k_rank<<<dim3(SLICES, BB), 256, 0, stream>>>(heat, cnts, prebuf,
                                                 rot_sine, rot_cosine, hei, dim, vel, reg,
                                                 (float*)d_out);
}